// Round 1
// baseline (690.632 us; speedup 1.0000x reference)
//
#include <hip/hip_runtime.h>

// Problem constants: B=32, S=2048, D=768, NL=512, NF=64
#define Bq 32
#define Sq 2048
#define Dq 768
#define NLq 512
#define NFq 64
#define SCHUNKS 16   // S / 128
#define LCHUNKS 8    // NL / 64

typedef unsigned short u16;
typedef unsigned int u32;
typedef __attribute__((ext_vector_type(4))) unsigned short us4;
typedef __attribute__((ext_vector_type(4))) unsigned int u32x4;
typedef __attribute__((ext_vector_type(8))) short s16x8;
typedef __attribute__((ext_vector_type(4))) float f32x4;

static __device__ __forceinline__ u16 f2bf(float f) {
  unsigned int u = __builtin_bit_cast(unsigned int, f);
  u += 0x7fffu + ((u >> 16) & 1u);  // round-to-nearest-even
  return (u16)(u >> 16);
}

// async global->LDS, 16 B per lane; LDS dest = wave-uniform base + lane*16
static __device__ __forceinline__ void gload16(const void* g, void* l) {
  __builtin_amdgcn_global_load_lds(
      (const __attribute__((address_space(1))) unsigned int*)g,
      (__attribute__((address_space(3))) unsigned int*)l, 16, 0, 0);
}

// K0: W [K,N] fp32 row-major -> Wt [N,K] bf16 row-major
__global__ __launch_bounds__(256) void wt_kernel(const float* __restrict__ W,
                                                 u16* __restrict__ Wt) {
  int idx = blockIdx.x * 256 + threadIdx.x;
  int n = idx / Dq, k = idx % Dq;
  Wt[idx] = f2bf(W[(size_t)k * Dq + n]);
}

// K1: C[M,N] = A@Wt^T + bias. A is read as fp32 directly (cvta fused: staged
// fp32 via global_load_lds with source-side XOR granule swizzle, converted to
// bf16 at fragment build with v_cvt_pk_bf16_f32). Epilogue additionally:
//   - per-128-row column sums -> part16 (for the exclusive chunk scan)
//   - intra-tile inclusive column cumsum -> pre ("precsum"), replacing the
//     separate csum kernel. cs(s) = off2[(s-1)>>7] + pre[s-1] at the consumer.
__global__ __launch_bounds__(256, 3) void gemm_kernel(const float* __restrict__ A,
                                                      const u16* __restrict__ Wt,
                                                      const float* __restrict__ bias,
                                                      float* __restrict__ C,
                                                      float* __restrict__ pre,
                                                      float* __restrict__ part16) {
  __shared__ float Asf[128 * 32];  // fp32 A tile, rows of 8x16B granules, XOR-swizzled
  __shared__ u16 Bs[128 * 32];     // [n][k] bf16, linear (as before)
  __shared__ float ps[2][128];
  const int tid = threadIdx.x;
  const int gn0 = blockIdx.x * 128;
  const int gm0 = blockIdx.y * 128;
  const int wave = tid >> 6, lane = tid & 63;
  const int lm = lane & 15, quad = lane >> 4;
  const int wm = (wave & 1) * 64, wn = (wave >> 1) * 64;

  // A staging: 4 gload16 calls/K-step; call c covers rows c*32 + (tid>>3).
  // LDS slot (r, h) receives global granule h ^ (r&7)  (involution; read
  // side applies the same XOR). Per-thread source granule is constant.
  const int arow = tid >> 3;                       // 0..31
  const int ah = (tid & 7) ^ (arow & 7);           // swizzled source granule
  const size_t astride = (size_t)Dq * 4;           // 3072 B row stride
  const char* ga = (const char*)A + (size_t)(gm0 + arow) * astride + ah * 16;
  // B staging: unchanged from the proven structure
  const char* gb0 = (const char*)Wt + (size_t)(gn0 + (tid >> 2)) * (Dq * 2) + (tid & 3) * 16;
  const char* gb1 = gb0 + (size_t)64 * (Dq * 2);
  char* lA = (char*)Asf + wave * 1024;  // wave-uniform; HW adds lane*16
  char* lB = (char*)Bs + wave * 1024;

  f32x4 acc[4][4] = {};
  const int ax = lm & 7;  // (row & 7) for all A fragment rows of this lane

  for (int kk = 0; kk < Dq / 32; ++kk) {
    __syncthreads();  // prev tile's ds_reads done
    gload16(ga, lA);
    gload16(ga + 32 * astride, lA + 4096);
    gload16(ga + 64 * astride, lA + 8192);
    gload16(ga + 96 * astride, lA + 12288);
    gload16(gb0, lB);
    gload16(gb1, lB + 4096);
    ga += 128; gb0 += 64; gb1 += 64;
    __syncthreads();  // vmcnt(0) drain: tile resident

    s16x8 af[4], bfr[4];
#pragma unroll
    for (int i = 0; i < 4; ++i) {
      const float* rowA = Asf + (wm + i * 16 + lm) * 32;
      // granule 2q holds floats [8q..8q+3], 2q+1 holds [8q+4..8q+7]
      f32x4 alo = *(const f32x4*)(rowA + (((2 * quad) ^ ax) << 2));
      f32x4 ahi = *(const f32x4*)(rowA + (((2 * quad + 1) ^ ax) << 2));
      u32 p0, p1, p2, p3;
      asm("v_cvt_pk_bf16_f32 %0, %1, %2" : "=v"(p0) : "v"(alo.x), "v"(alo.y));
      asm("v_cvt_pk_bf16_f32 %0, %1, %2" : "=v"(p1) : "v"(alo.z), "v"(alo.w));
      asm("v_cvt_pk_bf16_f32 %0, %1, %2" : "=v"(p2) : "v"(ahi.x), "v"(ahi.y));
      asm("v_cvt_pk_bf16_f32 %0, %1, %2" : "=v"(p3) : "v"(ahi.z), "v"(ahi.w));
      u32x4 u;
      u.x = p0; u.y = p1; u.z = p2; u.w = p3;
      af[i] = __builtin_bit_cast(s16x8, u);
    }
#pragma unroll
    for (int i = 0; i < 4; ++i)
      bfr[i] = *(const s16x8*)&Bs[(wn + i * 16 + lm) * 32 + quad * 8];
#pragma unroll
    for (int mi = 0; mi < 4; ++mi)
#pragma unroll
      for (int ni = 0; ni < 4; ++ni)
        acc[mi][ni] = __builtin_amdgcn_mfma_f32_16x16x32_bf16(af[mi], bfr[ni],
                                                              acc[mi][ni], 0, 0, 0);
  }

  // epilogue 1: C write + column sums (unchanged). ps[0][col] doubles as the
  // lower-half (rows 0..63) column total needed by the cumsum pass below.
#pragma unroll
  for (int ni = 0; ni < 4; ++ni) {
    const int gn = gn0 + wn + ni * 16 + lm;
    const float bv = bias[gn];
    float psum = 0.f;
#pragma unroll
    for (int mi = 0; mi < 4; ++mi) {
#pragma unroll
      for (int r = 0; r < 4; ++r) {
        const int gm = gm0 + wm + mi * 16 + quad * 4 + r;
        const float cv = acc[mi][ni][r] + bv;
        C[(size_t)gm * Dq + gn] = cv;
        psum += cv;
      }
    }
    psum += __shfl_xor(psum, 16);
    psum += __shfl_xor(psum, 32);
    if (lane < 16) ps[wave & 1][wn + ni * 16 + lm] = psum;
  }
  __syncthreads();
  if (tid < 128) {
    const int b = gm0 >> 11;            // /2048
    const int sc = (gm0 >> 7) & 15;     // 128-row chunk within b
    part16[((size_t)b * SCHUNKS + sc) * Dq + gn0 + tid] = ps[0][tid] + ps[1][tid];
  }

  // epilogue 2: inclusive column cumsum P over the 128 tile rows -> pre.
  // Lane holds rows {mi*16 + quad*4 + r} of its column. Hierarchy:
  // running r within quad -> shfl_up scan across 4 quads -> scalar prefix
  // across mi blocks -> ps[0][col] as the upper-half base.
#pragma unroll
  for (int ni = 0; ni < 4; ++ni) {
    const int col = wn + ni * 16 + lm;
    const float bv = bias[gn0 + col];
    float em = wm ? ps[0][col] : 0.f;  // rows-below-this-wave column total
#pragma unroll
    for (int mi = 0; mi < 4; ++mi) {
      const float v0 = acc[mi][ni][0] + bv, v1 = acc[mi][ni][1] + bv,
                  v2 = acc[mi][ni][2] + bv, v3 = acc[mi][ni][3] + bv;
      const float qs = v0 + v1 + v2 + v3;
      const float t1 = __shfl_up(qs, 16);
      const float i1 = qs + (quad >= 1 ? t1 : 0.f);
      const float t2 = __shfl_up(i1, 32);
      const float iq = i1 + (quad >= 2 ? t2 : 0.f);   // inclusive across quads
      const float eq = iq - qs;                       // exclusive across quads
      const float tot = __shfl(iq, 48 + lm);          // 16-row block total
      const float base = em + eq;
      em += tot;
      const float P0 = base + v0, P1 = P0 + v1, P2 = P1 + v2, P3 = P2 + v3;
      const size_t rowb = (size_t)(gm0 + wm + mi * 16 + quad * 4) * Dq + gn0 + col;
      pre[rowb] = P0;
      pre[rowb + Dq] = P1;
      pre[rowb + 2 * (size_t)Dq] = P2;
      pre[rowb + 3 * (size_t)Dq] = P3;
    }
  }
}

// K2: in-place exclusive scan over chunks per (b,d) column
__global__ __launch_bounds__(256) void scan_kernel(float* __restrict__ p, int C) {
  const int idx = blockIdx.x * 256 + threadIdx.x;  // B*D = 24576
  const int b = idx / Dq, d = idx % Dq;
  float run = 0.f;
  for (int c = 0; c < C; ++c) {
    const size_t o = ((size_t)b * C + c) * Dq + d;
    const float v = p[o];
    p[o] = run;
    run += v;
  }
}

// K3: line means (64 lines per block) + per-chunk line sums for lcsum scan.
// cs(s) reconstructed as s==0 ? 0 : off2[(s-1)>>7] + pre[b, s-1, d], with the
// 16 chunk offsets (off2 = scanned part16) staged in LDS.
__global__ __launch_bounds__(64) void line_kernel(const float* __restrict__ pre,
                                                  const float* __restrict__ part,
                                                  const int* __restrict__ lb,
                                                  float* __restrict__ lemb,
                                                  float* __restrict__ lpart) {
  __shared__ int sb[128];
  __shared__ float soff[SCHUNKS][64];
  const int lc = blockIdx.x, d64 = blockIdx.y, b = blockIdx.z;
  const int tid = threadIdx.x;
  if (tid < 32)
    ((int4*)sb)[tid] = ((const int4*)(lb + ((size_t)b * NLq + lc * 64) * 2))[tid];
  const int d = d64 * 64 + tid;
#pragma unroll
  for (int sc = 0; sc < SCHUNKS; ++sc)
    soff[sc][tid] = part[((size_t)b * SCHUNKS + sc) * Dq + d];
  __syncthreads();
  const float* pb = pre + (size_t)b * Sq * Dq + d;
  float* le = lemb + ((size_t)b * NLq + lc * 64) * Dq + d;
  float sum = 0.f;
  for (int n0 = 0; n0 < 64; n0 += 8) {
    float vs[8], ve[8];
    int len[8];
#pragma unroll
    for (int i = 0; i < 8; ++i) {
      const int s0 = sb[2 * (n0 + i)], s1 = sb[2 * (n0 + i) + 1];
      len[i] = s1 - s0;
      const int t0 = s0 > 0 ? s0 - 1 : 0;  // clamped, load always safe
      const int t1 = s1 > 0 ? s1 - 1 : 0;
      const float a0 = pb[(size_t)t0 * Dq] + soff[t0 >> 7][tid];
      const float a1 = pb[(size_t)t1 * Dq] + soff[t1 >> 7][tid];
      vs[i] = s0 > 0 ? a0 : 0.f;  // cs(0) = 0 (s uniform across lanes)
      ve[i] = a1;                 // len>0 implies s1>=1; len<=0 path yields 0 anyway
    }
#pragma unroll
    for (int i = 0; i < 8; ++i) {
      const float v = len[i] > 0 ? (ve[i] - vs[i]) / (float)len[i] : 0.f;
      le[(size_t)(n0 + i) * Dq] = v;
      sum += v;
    }
  }
  lpart[((size_t)b * LCHUNKS + lc) * Dq + d] = sum;
}

// K5: lcsum rows from lemb + scanned chunk offsets
__global__ __launch_bounds__(256) void lcsum_kernel(const float* __restrict__ lemb,
                                                    const float* __restrict__ lpart,
                                                    float* __restrict__ lcsum) {
  const int lc = blockIdx.x, dc = blockIdx.y, b = blockIdx.z;
  const int d = dc * 256 + threadIdx.x;
  const float* src = lemb + ((size_t)b * NLq + lc * 64) * Dq + d;
  float* dst = lcsum + ((size_t)b * (NLq + 1) + lc * 64 + 1) * Dq + d;
  float run = lpart[((size_t)b * LCHUNKS + lc) * Dq + d];
  if (lc == 0) lcsum[(size_t)b * (NLq + 1) * Dq + d] = 0.f;
  for (int n0 = 0; n0 < 64; n0 += 8) {
    float v[8];
#pragma unroll
    for (int i = 0; i < 8; ++i) v[i] = src[(size_t)(n0 + i) * Dq];
#pragma unroll
    for (int i = 0; i < 8; ++i) {
      run += v[i];
      dst[(size_t)(n0 + i) * Dq] = run;
    }
  }
}

// K6: func_emb from lcsum gather + file_emb = mean over 64 functions
__global__ __launch_bounds__(64) void func_kernel(const float* __restrict__ lcsum,
                                                  const int* __restrict__ fb,
                                                  float* __restrict__ femb,
                                                  float* __restrict__ file) {
  __shared__ int sb[NFq * 2];
  const int tid = threadIdx.x;
  const int d64 = blockIdx.x, b = blockIdx.y;
  const int d = d64 * 64 + tid;
  if (tid < NFq * 2 / 4)
    ((int4*)sb)[tid] = ((const int4*)(fb + (size_t)b * NFq * 2))[tid];
  __syncthreads();
  const float* lc = lcsum + (size_t)b * (NLq + 1) * Dq + d;
  float* fe = femb + (size_t)b * NFq * Dq + d;
  float acc = 0.f;
#pragma unroll 8
  for (int f = 0; f < NFq; ++f) {
    const int l0 = sb[2 * f], l1 = sb[2 * f + 1];
    const float v = l1 > l0 ? (lc[(size_t)l1 * Dq] - lc[(size_t)l0 * Dq]) / (float)(l1 - l0)
                            : 0.f;
    fe[(size_t)f * Dq] = v;
    acc += v;
  }
  file[(size_t)b * Dq + d] = acc * (1.f / (float)NFq);
}

extern "C" void kernel_launch(void* const* d_in, const int* in_sizes, int n_in,
                              void* d_out, int out_size, void* d_ws, size_t ws_size,
                              hipStream_t stream) {
  const float* hs   = (const float*)d_in[0];  // [B,S,D] fp32
  const float* W    = (const float*)d_in[1];  // [D,D] fp32
  const float* bias = (const float*)d_in[2];  // [D] fp32
  const int* lb     = (const int*)d_in[3];    // [B,NL,2] int32
  const int* fb     = (const int*)d_in[4];    // [B,NF,2] int32

  float* out = (float*)d_out;
  float* token = out;                                         // B*S*D
  float* line  = token + (size_t)Bq * Sq * Dq;                // B*NL*D
  float* func  = line + (size_t)Bq * NLq * Dq;                // B*NF*D
  float* file  = func + (size_t)Bq * NFq * Dq;                // B*D

  // Workspace layout (253,120,512 B), stream-order-safe aliasing:
  //   [0, 201.3MB)   precsum fp32 [B,S,D]  (written by gemm, read by line)
  //   [201.5, 251.9) lcsum fp32            | part16 (1.57MB; line reads it as
  //                                          off2 before lcsum overwrites)
  //   [251.9, 253.1) Wt bf16 (1.18MB)      | lpart (written after gemm read Wt)
  char* ws = (char*)d_ws;
  float* precsum = (float*)ws;
  float* lcsum   = (float*)(ws + 201498624);
  float* part16  = lcsum;
  u16*   Wt      = (u16*)(ws + 201498624 + 50442240);
  float* lpart   = (float*)Wt;

  wt_kernel<<<(Dq * Dq) / 256, 256, 0, stream>>>(W, Wt);
  gemm_kernel<<<dim3(Dq / 128, (Bq * Sq) / 128), 256, 0, stream>>>(hs, Wt, bias, token,
                                                                   precsum, part16);
  scan_kernel<<<(Bq * Dq) / 256, 256, 0, stream>>>(part16, SCHUNKS);
  line_kernel<<<dim3(LCHUNKS, 12, Bq), 64, 0, stream>>>(precsum, part16, lb, line, lpart);
  scan_kernel<<<(Bq * Dq) / 256, 256, 0, stream>>>(lpart, LCHUNKS);
  lcsum_kernel<<<dim3(LCHUNKS, 3, Bq), 256, 0, stream>>>(line, lpart, lcsum);
  func_kernel<<<dim3(12, Bq), 64, 0, stream>>>(lcsum, fb, func, file);
}

// Round 2
// 649.986 us; speedup vs baseline: 1.0625x; 1.0625x over previous
//
#include <hip/hip_runtime.h>

// Problem constants: B=32, S=2048, D=768, NL=512, NF=64
#define Bq 32
#define Sq 2048
#define Dq 768
#define NLq 512
#define NFq 64
#define SCHUNKS 16   // S / 128
#define LCHUNKS 8    // NL / 64

typedef unsigned short u16;
typedef unsigned int u32;
typedef __attribute__((ext_vector_type(4))) unsigned short us4;
typedef __attribute__((ext_vector_type(4))) unsigned int u32x4;
typedef __attribute__((ext_vector_type(8))) short s16x8;
typedef __attribute__((ext_vector_type(4))) float f32x4;

static __device__ __forceinline__ u16 f2bf(float f) {
  unsigned int u = __builtin_bit_cast(unsigned int, f);
  u += 0x7fffu + ((u >> 16) & 1u);  // round-to-nearest-even
  return (u16)(u >> 16);
}

// async global->LDS, 16 B per lane; LDS dest = wave-uniform base + lane*16
static __device__ __forceinline__ void gload16(const void* g, void* l) {
  __builtin_amdgcn_global_load_lds(
      (const __attribute__((address_space(1))) unsigned int*)g,
      (__attribute__((address_space(3))) unsigned int*)l, 16, 0, 0);
}

// K0: W [K,N] fp32 row-major -> Wt [N,K] bf16 row-major
__global__ __launch_bounds__(256) void wt_kernel(const float* __restrict__ W,
                                                 u16* __restrict__ Wt) {
  int idx = blockIdx.x * 256 + threadIdx.x;
  int n = idx / Dq, k = idx % Dq;
  Wt[idx] = f2bf(W[(size_t)k * Dq + n]);
}

// K1: C[M,N] = A@Wt^T + bias. fp32 A staged via global_load_lds with
// source-side XOR granule swizzle, converted at fragment build with
// v_cvt_pk_bf16_f32. Double-buffered K-loop (stage t+1 || compute t, one
// __syncthreads per step = the vmcnt/lgkm drain). XCD-chunked blockIdx
// swizzle co-locates the 6 n-tiles of each row-panel on one XCD's L2.
// Epilogue: C+bias write, per-128-row column sums -> part16, intra-tile
// inclusive column cumsum -> pre.
__global__ __launch_bounds__(256, 3) void gemm_kernel(const float* __restrict__ A,
                                                      const u16* __restrict__ Wt,
                                                      const float* __restrict__ bias,
                                                      float* __restrict__ C,
                                                      float* __restrict__ pre,
                                                      float* __restrict__ part16) {
  __shared__ float Asf[2][128 * 32];  // fp32 A tiles, XOR-swizzled granules
  __shared__ u16 Bs[2][128 * 32];     // [n][k] bf16, linear
  __shared__ float ps[2][128];
  const int tid = threadIdx.x;
  // XCD-chunked swizzle: hw dispatch index bid -> logical lid so that each
  // XCD (bid&7) gets 384 consecutive lids = 64 row-panels x 6 n-tiles.
  const int bid = blockIdx.y * gridDim.x + blockIdx.x;  // 0..3071, x fastest
  const int lid = (bid & 7) * 384 + (bid >> 3);         // bijective (3072%8==0)
  const int gn0 = (lid % 6) * 128;
  const int gm0 = (lid / 6) * 128;
  const int wave = tid >> 6, lane = tid & 63;
  const int lm = lane & 15, quad = lane >> 4;
  const int wm = (wave & 1) * 64, wn = (wave >> 1) * 64;

  // A staging: 4 gload16/K-step; call c covers rows c*32 + (tid>>3).
  // LDS slot (r, h) receives global granule h ^ (r&7) (involution; the read
  // side applies the same XOR). Per-thread source granule is constant.
  const int arow = tid >> 3;                       // 0..31
  const int ah = (tid & 7) ^ (arow & 7);           // swizzled source granule
  const size_t astride = (size_t)Dq * 4;           // 3072 B row stride
  const char* ga = (const char*)A + (size_t)(gm0 + arow) * astride + ah * 16;
  const char* gb0 = (const char*)Wt + (size_t)(gn0 + (tid >> 2)) * (Dq * 2) + (tid & 3) * 16;
  const char* gb1 = gb0 + (size_t)64 * (Dq * 2);

  f32x4 acc[4][4] = {};
  const int ax = lm & 7;  // (row & 7) for all A fragment rows of this lane

  auto stage = [&](int t, int buf) {
    char* lA = (char*)&Asf[buf][0] + wave * 1024;  // wave-uniform; HW adds lane*16
    char* lB = (char*)&Bs[buf][0] + wave * 1024;
    const char* gat = ga + t * 128;
    gload16(gat, lA);
    gload16(gat + 32 * astride, lA + 4096);
    gload16(gat + 64 * astride, lA + 8192);
    gload16(gat + 96 * astride, lA + 12288);
    gload16(gb0 + t * 64, lB);
    gload16(gb1 + t * 64, lB + 4096);
  };

  stage(0, 0);
  __syncthreads();  // tile 0 resident

  for (int t = 0; t < Dq / 32; ++t) {
    if (t < Dq / 32 - 1) stage(t + 1, (t + 1) & 1);  // in flight under compute
    const int buf = t & 1;

    s16x8 af[4], bfr[4];
#pragma unroll
    for (int i = 0; i < 4; ++i) {
      const float* rowA = &Asf[buf][(wm + i * 16 + lm) * 32];
      // granule 2q holds floats [8q..8q+3], 2q+1 holds [8q+4..8q+7]
      f32x4 alo = *(const f32x4*)(rowA + (((2 * quad) ^ ax) << 2));
      f32x4 ahi = *(const f32x4*)(rowA + (((2 * quad + 1) ^ ax) << 2));
      u32 p0, p1, p2, p3;
      asm("v_cvt_pk_bf16_f32 %0, %1, %2" : "=v"(p0) : "v"(alo.x), "v"(alo.y));
      asm("v_cvt_pk_bf16_f32 %0, %1, %2" : "=v"(p1) : "v"(alo.z), "v"(alo.w));
      asm("v_cvt_pk_bf16_f32 %0, %1, %2" : "=v"(p2) : "v"(ahi.x), "v"(ahi.y));
      asm("v_cvt_pk_bf16_f32 %0, %1, %2" : "=v"(p3) : "v"(ahi.z), "v"(ahi.w));
      u32x4 u;
      u.x = p0; u.y = p1; u.z = p2; u.w = p3;
      af[i] = __builtin_bit_cast(s16x8, u);
    }
#pragma unroll
    for (int i = 0; i < 4; ++i)
      bfr[i] = *(const s16x8*)&Bs[buf][(wn + i * 16 + lm) * 32 + quad * 8];
#pragma unroll
    for (int mi = 0; mi < 4; ++mi)
#pragma unroll
      for (int ni = 0; ni < 4; ++ni)
        acc[mi][ni] = __builtin_amdgcn_mfma_f32_16x16x32_bf16(af[mi], bfr[ni],
                                                              acc[mi][ni], 0, 0, 0);
    __syncthreads();  // drains vmcnt (stage t+1 resident) + all ds_reads of buf
  }

  // epilogue 1: C write + column sums. ps[0][col] doubles as the lower-half
  // (rows 0..63) column total needed by the cumsum pass below.
#pragma unroll
  for (int ni = 0; ni < 4; ++ni) {
    const int gn = gn0 + wn + ni * 16 + lm;
    const float bv = bias[gn];
    float psum = 0.f;
#pragma unroll
    for (int mi = 0; mi < 4; ++mi) {
#pragma unroll
      for (int r = 0; r < 4; ++r) {
        const int gm = gm0 + wm + mi * 16 + quad * 4 + r;
        const float cv = acc[mi][ni][r] + bv;
        C[(size_t)gm * Dq + gn] = cv;
        psum += cv;
      }
    }
    psum += __shfl_xor(psum, 16);
    psum += __shfl_xor(psum, 32);
    if (lane < 16) ps[wave & 1][wn + ni * 16 + lm] = psum;
  }
  __syncthreads();
  if (tid < 128) {
    const int b = gm0 >> 11;            // /2048
    const int sc = (gm0 >> 7) & 15;     // 128-row chunk within b
    part16[((size_t)b * SCHUNKS + sc) * Dq + gn0 + tid] = ps[0][tid] + ps[1][tid];
  }

  // epilogue 2: inclusive column cumsum P over the 128 tile rows -> pre.
  // running r within quad -> shfl_up scan across 4 quads -> scalar prefix
  // across mi blocks -> ps[0][col] as the upper-half base.
#pragma unroll
  for (int ni = 0; ni < 4; ++ni) {
    const int col = wn + ni * 16 + lm;
    const float bv = bias[gn0 + col];
    float em = wm ? ps[0][col] : 0.f;  // rows-below-this-wave column total
#pragma unroll
    for (int mi = 0; mi < 4; ++mi) {
      const float v0 = acc[mi][ni][0] + bv, v1 = acc[mi][ni][1] + bv,
                  v2 = acc[mi][ni][2] + bv, v3 = acc[mi][ni][3] + bv;
      const float qs = v0 + v1 + v2 + v3;
      const float t1 = __shfl_up(qs, 16);
      const float i1 = qs + (quad >= 1 ? t1 : 0.f);
      const float t2 = __shfl_up(i1, 32);
      const float iq = i1 + (quad >= 2 ? t2 : 0.f);   // inclusive across quads
      const float eq = iq - qs;                       // exclusive across quads
      const float tot = __shfl(iq, 48 + lm);          // 16-row block total
      const float base = em + eq;
      em += tot;
      const float P0 = base + v0, P1 = P0 + v1, P2 = P1 + v2, P3 = P2 + v3;
      const size_t rowb = (size_t)(gm0 + wm + mi * 16 + quad * 4) * Dq + gn0 + col;
      pre[rowb] = P0;
      pre[rowb + Dq] = P1;
      pre[rowb + 2 * (size_t)Dq] = P2;
      pre[rowb + 3 * (size_t)Dq] = P3;
    }
  }
}

// K2: in-place exclusive scan over chunks per (b,d) column
__global__ __launch_bounds__(256) void scan_kernel(float* __restrict__ p, int C) {
  const int idx = blockIdx.x * 256 + threadIdx.x;  // B*D = 24576
  const int b = idx / Dq, d = idx % Dq;
  float run = 0.f;
  for (int c = 0; c < C; ++c) {
    const size_t o = ((size_t)b * C + c) * Dq + d;
    const float v = p[o];
    p[o] = run;
    run += v;
  }
}

// K3: line means (64 lines per block) + per-chunk line sums for lcsum scan.
// cs(s) reconstructed as s==0 ? 0 : off2[(s-1)>>7] + pre[b, s-1, d], with the
// 16 chunk offsets (off2 = scanned part16) staged in LDS.
__global__ __launch_bounds__(64) void line_kernel(const float* __restrict__ pre,
                                                  const float* __restrict__ part,
                                                  const int* __restrict__ lb,
                                                  float* __restrict__ lemb,
                                                  float* __restrict__ lpart) {
  __shared__ int sb[128];
  __shared__ float soff[SCHUNKS][64];
  const int lc = blockIdx.x, d64 = blockIdx.y, b = blockIdx.z;
  const int tid = threadIdx.x;
  if (tid < 32)
    ((int4*)sb)[tid] = ((const int4*)(lb + ((size_t)b * NLq + lc * 64) * 2))[tid];
  const int d = d64 * 64 + tid;
#pragma unroll
  for (int sc = 0; sc < SCHUNKS; ++sc)
    soff[sc][tid] = part[((size_t)b * SCHUNKS + sc) * Dq + d];
  __syncthreads();
  const float* pb = pre + (size_t)b * Sq * Dq + d;
  float* le = lemb + ((size_t)b * NLq + lc * 64) * Dq + d;
  float sum = 0.f;
  for (int n0 = 0; n0 < 64; n0 += 8) {
    float vs[8], ve[8];
    int len[8];
#pragma unroll
    for (int i = 0; i < 8; ++i) {
      const int s0 = sb[2 * (n0 + i)], s1 = sb[2 * (n0 + i) + 1];
      len[i] = s1 - s0;
      const int t0 = s0 > 0 ? s0 - 1 : 0;  // clamped, load always safe
      const int t1 = s1 > 0 ? s1 - 1 : 0;
      const float a0 = pb[(size_t)t0 * Dq] + soff[t0 >> 7][tid];
      const float a1 = pb[(size_t)t1 * Dq] + soff[t1 >> 7][tid];
      vs[i] = s0 > 0 ? a0 : 0.f;  // cs(0) = 0 (s uniform across lanes)
      ve[i] = a1;                 // len>0 implies s1>=1; len<=0 path yields 0 anyway
    }
#pragma unroll
    for (int i = 0; i < 8; ++i) {
      const float v = len[i] > 0 ? (ve[i] - vs[i]) / (float)len[i] : 0.f;
      le[(size_t)(n0 + i) * Dq] = v;
      sum += v;
    }
  }
  lpart[((size_t)b * LCHUNKS + lc) * Dq + d] = sum;
}

// K5: lcsum rows from lemb + scanned chunk offsets
__global__ __launch_bounds__(256) void lcsum_kernel(const float* __restrict__ lemb,
                                                    const float* __restrict__ lpart,
                                                    float* __restrict__ lcsum) {
  const int lc = blockIdx.x, dc = blockIdx.y, b = blockIdx.z;
  const int d = dc * 256 + threadIdx.x;
  const float* src = lemb + ((size_t)b * NLq + lc * 64) * Dq + d;
  float* dst = lcsum + ((size_t)b * (NLq + 1) + lc * 64 + 1) * Dq + d;
  float run = lpart[((size_t)b * LCHUNKS + lc) * Dq + d];
  if (lc == 0) lcsum[(size_t)b * (NLq + 1) * Dq + d] = 0.f;
  for (int n0 = 0; n0 < 64; n0 += 8) {
    float v[8];
#pragma unroll
    for (int i = 0; i < 8; ++i) v[i] = src[(size_t)(n0 + i) * Dq];
#pragma unroll
    for (int i = 0; i < 8; ++i) {
      run += v[i];
      dst[(size_t)(n0 + i) * Dq] = run;
    }
  }
}

// K6: func_emb from lcsum gather + file_emb = mean over 64 functions
__global__ __launch_bounds__(64) void func_kernel(const float* __restrict__ lcsum,
                                                  const int* __restrict__ fb,
                                                  float* __restrict__ femb,
                                                  float* __restrict__ file) {
  __shared__ int sb[NFq * 2];
  const int tid = threadIdx.x;
  const int d64 = blockIdx.x, b = blockIdx.y;
  const int d = d64 * 64 + tid;
  if (tid < NFq * 2 / 4)
    ((int4*)sb)[tid] = ((const int4*)(fb + (size_t)b * NFq * 2))[tid];
  __syncthreads();
  const float* lc = lcsum + (size_t)b * (NLq + 1) * Dq + d;
  float* fe = femb + (size_t)b * NFq * Dq + d;
  float acc = 0.f;
#pragma unroll 8
  for (int f = 0; f < NFq; ++f) {
    const int l0 = sb[2 * f], l1 = sb[2 * f + 1];
    const float v = l1 > l0 ? (lc[(size_t)l1 * Dq] - lc[(size_t)l0 * Dq]) / (float)(l1 - l0)
                            : 0.f;
    fe[(size_t)f * Dq] = v;
    acc += v;
  }
  file[(size_t)b * Dq + d] = acc * (1.f / (float)NFq);
}

extern "C" void kernel_launch(void* const* d_in, const int* in_sizes, int n_in,
                              void* d_out, int out_size, void* d_ws, size_t ws_size,
                              hipStream_t stream) {
  const float* hs   = (const float*)d_in[0];  // [B,S,D] fp32
  const float* W    = (const float*)d_in[1];  // [D,D] fp32
  const float* bias = (const float*)d_in[2];  // [D] fp32
  const int* lb     = (const int*)d_in[3];    // [B,NL,2] int32
  const int* fb     = (const int*)d_in[4];    // [B,NF,2] int32

  float* out = (float*)d_out;
  float* token = out;                                         // B*S*D
  float* line  = token + (size_t)Bq * Sq * Dq;                // B*NL*D
  float* func  = line + (size_t)Bq * NLq * Dq;                // B*NF*D
  float* file  = func + (size_t)Bq * NFq * Dq;                // B*D

  // Workspace layout, stream-order-safe aliasing:
  //   [0, 201.3MB)   precsum fp32 [B,S,D]  (written by gemm, read by line)
  //   [201.5, 251.9) lcsum fp32            | part16 (1.57MB; line reads it as
  //                                          off2 before lcsum overwrites)
  //   [251.9, 253.1) Wt bf16 (1.18MB)      | lpart (written after gemm read Wt)
  char* ws = (char*)d_ws;
  float* precsum = (float*)ws;
  float* lcsum   = (float*)(ws + 201498624);
  float* part16  = lcsum;
  u16*   Wt      = (u16*)(ws + 201498624 + 50442240);
  float* lpart   = (float*)Wt;

  wt_kernel<<<(Dq * Dq) / 256, 256, 0, stream>>>(W, Wt);
  gemm_kernel<<<dim3(Dq / 128, (Bq * Sq) / 128), 256, 0, stream>>>(hs, Wt, bias, token,
                                                                   precsum, part16);
  scan_kernel<<<(Bq * Dq) / 256, 256, 0, stream>>>(part16, SCHUNKS);
  line_kernel<<<dim3(LCHUNKS, 12, Bq), 64, 0, stream>>>(precsum, part16, lb, line, lpart);
  scan_kernel<<<(Bq * Dq) / 256, 256, 0, stream>>>(lpart, LCHUNKS);
  lcsum_kernel<<<dim3(LCHUNKS, 3, Bq), 256, 0, stream>>>(line, lpart, lcsum);
  func_kernel<<<dim3(12, Bq), 64, 0, stream>>>(lcsum, fb, func, file);
}